// Round 3
// baseline (31.564 us; speedup 1.0000x reference)
//
#include <hip/hip_runtime.h>

typedef _Float16 half2_t __attribute__((ext_vector_type(2)));

#define G 512
#define N 24
#define DD 12288
#define DIM 64
#define HL 3

__global__ __launch_bounds__(512)
void gnn_mol_kernel(const int* __restrict__ fp,
                    const float* __restrict__ A,
                    const float* __restrict__ emb,
                    const float* __restrict__ W_fp,
                    const float* __restrict__ b_fp,
                    const float* __restrict__ W_out,
                    const float* __restrict__ b_out,
                    const float* __restrict__ W_prop,
                    const float* __restrict__ b_prop,
                    float* __restrict__ out)
{
    const int g = blockIdx.x;
    const int t = threadIdx.x;
    const int j = t & 63;                                   // column 0..63
    const int w = __builtin_amdgcn_readfirstlane(t >> 6);   // wave 0..7 (uniform)
    const int a0 = 3 * w;                                   // this wave's 3 atoms

    __shared__ _Float16 xs[N][DIM];   // 3 KB  (f16 copy of x, read via b128)
    __shared__ float    hs[N][DIM];   // 6 KB  (relu(linear(x)))
    __shared__ float    ps[8][DIM];   // 2 KB  (per-wave segsum partials)
    __shared__ float    msh[DIM];
    __shared__ float    ysh[DIM];
    __shared__ float    zsh[DIM];

    const long srow = (long)g * N;
    // Wave-uniform base of this molecule's diagonal A block (scalar-cache path)
    const float* __restrict__ Abase = A + srow * (long)DD + srow;

    // ---- embedding gather: x[a][j] = emb[fp[a]][j] ----
    float xv[3];
    #pragma unroll
    for (int i = 0; i < 3; ++i) {
        int a = a0 + i;
        int f = fp[g * N + a];                 // uniform -> s_load
        float v = emb[(long)f * DIM + j];      // coalesced 256B/wave
        xv[i] = v;
        xs[a][j] = (_Float16)v;
    }
    __syncthreads();

    for (int layer = 0; layer < HL; ++layer) {
        // ---- pack W row j (fp32 global, L1-hot) into 32 half2 registers ----
        const float* Wl = W_fp + layer * DIM * DIM + j * DIM;
        half2_t w2[32];
        #pragma unroll
        for (int k4 = 0; k4 < 16; ++k4) {
            float4 wv = *(const float4*)(Wl + 4 * k4);
            w2[2 * k4]     = __builtin_bit_cast(half2_t, __builtin_amdgcn_cvt_pkrtz(wv.x, wv.y));
            w2[2 * k4 + 1] = __builtin_bit_cast(half2_t, __builtin_amdgcn_cvt_pkrtz(wv.z, wv.w));
        }
        float bias = b_fp[layer * DIM + j];

        // ---- linear: h[a][j] = relu(b[j] + sum_k x[a][k] * W[j][k]) via dot2 ----
        #pragma unroll
        for (int i = 0; i < 3; ++i) {
            int a = a0 + i;
            float acc0 = bias, acc1 = 0.f, acc2 = 0.f, acc3 = 0.f;
            #pragma unroll
            for (int q = 0; q < 8; ++q) {
                uint4 qv = *(const uint4*)(&xs[a][8 * q]);   // broadcast b128: 8 halves
                half2_t x0 = __builtin_bit_cast(half2_t, qv.x);
                half2_t x1 = __builtin_bit_cast(half2_t, qv.y);
                half2_t x2 = __builtin_bit_cast(half2_t, qv.z);
                half2_t x3 = __builtin_bit_cast(half2_t, qv.w);
                acc0 = __builtin_amdgcn_fdot2(x0, w2[4 * q + 0], acc0, false);
                acc1 = __builtin_amdgcn_fdot2(x1, w2[4 * q + 1], acc1, false);
                acc2 = __builtin_amdgcn_fdot2(x2, w2[4 * q + 2], acc2, false);
                acc3 = __builtin_amdgcn_fdot2(x3, w2[4 * q + 3], acc3, false);
            }
            float h = fmaxf((acc0 + acc1) + (acc2 + acc3), 0.f);
            hs[a][j] = h;
        }
        __syncthreads();

        // ---- h column j -> registers (24x ds_read_b32, conflict-free) ----
        float hcol[N];
        #pragma unroll
        for (int b = 0; b < N; ++b) hcol[b] = hs[b][j];

        // ---- x[a][j] += sum_b A[a][b] * h[b][j]; A row via scalar loads ----
        #pragma unroll
        for (int i = 0; i < 3; ++i) {
            const float* __restrict__ Arow = Abase + (long)(a0 + i) * DD; // uniform
            float acc = 0.f;
            #pragma unroll
            for (int b = 0; b < N; ++b)
                acc = fmaf(Arow[b], hcol[b], acc);   // scalar A operand
            xv[i] += acc;
            xs[a0 + i][j] = (_Float16)xv[i];         // f16 copy for next layer
        }
        __syncthreads();
    }

    // ---- segment sum: mol[j] = sum_a x[a][j] (fp32 master values) ----
    ps[w][j] = xv[0] + xv[1] + xv[2];
    __syncthreads();
    if (t < DIM) {
        float m = 0.f;
        #pragma unroll
        for (int i = 0; i < 8; ++i) m += ps[i][t];
        msh[t] = m;
    }
    __syncthreads();

    // ---- output MLP layer 0 ----
    if (t < DIM) {
        float acc = b_out[t];
        #pragma unroll
        for (int k4 = 0; k4 < 16; ++k4) {
            float4 mv = *(const float4*)(&msh[4 * k4]);
            const float* Wr = W_out + t * DIM + 4 * k4;
            acc += mv.x * Wr[0] + mv.y * Wr[1] + mv.z * Wr[2] + mv.w * Wr[3];
        }
        ysh[t] = fmaxf(acc, 0.f);
    }
    __syncthreads();

    // ---- output MLP layer 1 ----
    if (t < DIM) {
        float acc = b_out[DIM + t];
        #pragma unroll
        for (int k4 = 0; k4 < 16; ++k4) {
            float4 yv = *(const float4*)(&ysh[4 * k4]);
            const float* Wr = W_out + DIM * DIM + t * DIM + 4 * k4;
            acc += yv.x * Wr[0] + yv.y * Wr[1] + yv.z * Wr[2] + yv.w * Wr[3];
        }
        zsh[t] = fmaxf(acc, 0.f);
    }
    __syncthreads();

    // ---- property head ----
    if (t < 2) {
        float acc = b_prop[t];
        #pragma unroll
        for (int k4 = 0; k4 < 16; ++k4) {
            float4 zv = *(const float4*)(&zsh[4 * k4]);
            const float* Wr = W_prop + t * DIM + 4 * k4;
            acc += zv.x * Wr[0] + zv.y * Wr[1] + zv.z * Wr[2] + zv.w * Wr[3];
        }
        out[g * 2 + t] = acc;
    }
}

extern "C" void kernel_launch(void* const* d_in, const int* in_sizes, int n_in,
                              void* d_out, int out_size, void* d_ws, size_t ws_size,
                              hipStream_t stream) {
    const int*   fp     = (const int*)  d_in[0];
    // d_in[1] segment_ids: implied by block index
    const float* A      = (const float*)d_in[2];
    const float* emb    = (const float*)d_in[3];
    const float* W_fp   = (const float*)d_in[4];
    const float* b_fp   = (const float*)d_in[5];
    const float* W_out  = (const float*)d_in[6];
    const float* b_out  = (const float*)d_in[7];
    const float* W_prop = (const float*)d_in[8];
    const float* b_prop = (const float*)d_in[9];
    float* out = (float*)d_out;

    gnn_mol_kernel<<<G, 512, 0, stream>>>(fp, A, emb, W_fp, b_fp,
                                          W_out, b_out, W_prop, b_prop, out);
}